// Round 1
// baseline (361.162 us; speedup 1.0000x reference)
//
#include <hip/hip_runtime.h>

#define BATCH 4096
#define FF 64
#define DD 256
#define PAD 264     // LDS row stride in bf16 elements: 528 B, 16B-aligned rows
#define NPAIR 2016  // 64*63/2

typedef __attribute__((ext_vector_type(8))) short short8;
typedef __attribute__((ext_vector_type(16))) float f32x16;

// fp32 -> bf16, round-to-nearest-even (inputs are finite random normals; no NaN path needed)
__device__ __forceinline__ unsigned short f2bf(float f) {
    unsigned int u = __float_as_uint(f);
    u += 0x7FFFu + ((u >> 16) & 1u);
    return (unsigned short)(u >> 16);
}

__global__ __launch_bounds__(256, 4) void gram_tri(const float* __restrict__ x,
                                                   float* __restrict__ out) {
    __shared__ __align__(16) unsigned short sX[FF * PAD];
    const int b = blockIdx.x;
    const int t = threadIdx.x;

    // ---- Stage 1: global fp32 -> bf16 LDS (coalesced float4 stream) ----
    const float4* __restrict__ src = (const float4*)(x + (size_t)b * (FF * DD));
#pragma unroll
    for (int it = 0; it < 16; ++it) {
        int idx = (it << 8) + t;        // float4 index within the 64x256 tile, 0..4095
        float4 v = src[idx];
        int r  = idx >> 6;              // 64 float4 per row
        int kq = idx & 63;
        ushort4 w;
        w.x = f2bf(v.x); w.y = f2bf(v.y); w.z = f2bf(v.z); w.w = f2bf(v.w);
        *(ushort4*)&sX[r * PAD + (kq << 2)] = w;   // 8B store, 8B-aligned, 2-way bank alias (free)
    }
    __syncthreads();

    // ---- Stage 2: 4 waves, each one 32x32 quadrant of C = X * X^T ----
    const int wave = t >> 6;
    const int lane = t & 63;
    const int qi = wave >> 1;
    const int qj = wave & 1;
    const int rA = (qi << 5) + (lane & 31);
    const int rB = (qj << 5) + (lane & 31);
    const int ks = (lane >> 5) << 3;    // k-offset 0 or 8 within each K=16 step

    f32x16 acc;
#pragma unroll
    for (int i = 0; i < 16; ++i) acc[i] = 0.0f;

    const unsigned short* pA = &sX[rA * PAD + ks];
    const unsigned short* pB = &sX[rB * PAD + ks];
#pragma unroll
    for (int ko = 0; ko < DD; ko += 16) {
        short8 a  = *(const short8*)(pA + ko);   // 16B-aligned ds_read_b128
        short8 bb = *(const short8*)(pB + ko);
        acc = __builtin_amdgcn_mfma_f32_32x32x16_bf16(a, bb, acc, 0, 0, 0);
    }

    // ---- Stage 3: predicated strict-upper-triangle store ----
    // C/D layout (verified m74/m101): col = lane&31, row = (reg&3) + 8*(reg>>2) + 4*(lane>>5)
    float* __restrict__ ob = out + (size_t)b * NPAIR;
#pragma unroll
    for (int reg = 0; reg < 16; ++reg) {
        int i = (qi << 5) + (reg & 3) + ((reg >> 2) << 3) + ((lane >> 5) << 2);
        int j = (qj << 5) + (lane & 31);
        if (i < j) {
            int p = i * 63 - ((i * (i - 1)) >> 1) + (j - i - 1);
            ob[p] = acc[reg];
        }
    }
}

extern "C" void kernel_launch(void* const* d_in, const int* in_sizes, int n_in,
                              void* d_out, int out_size, void* d_ws, size_t ws_size,
                              hipStream_t stream) {
    const float* x = (const float*)d_in[0];
    float* out = (float*)d_out;
    gram_tri<<<BATCH, 256, 0, stream>>>(x, out);
}

// Round 2
// 360.810 us; speedup vs baseline: 1.0010x; 1.0010x over previous
//
#include <hip/hip_runtime.h>

#define FF 64
#define DD 256
#define KC 128            // K-chunk (elements)
#define LSTR 136          // LDS row stride in bf16 elems: 272 B = 17×16 B (odd → conflict-free b128 reads)
#define NPAIR 2016        // 64*63/2
#define ROWS 4            // batch rows per block
#define NCHUNK (2 * ROWS)

typedef __attribute__((ext_vector_type(8))) short short8;
typedef __attribute__((ext_vector_type(16))) float f32x16;

// two fp32 -> packed bf16x2, round-to-nearest-even
__device__ __forceinline__ unsigned int pack2(float lo, float hi) {
    unsigned int a = __float_as_uint(lo);
    unsigned int b = __float_as_uint(hi);
    a += 0x7FFFu + ((a >> 16) & 1u);
    b += 0x7FFFu + ((b >> 16) & 1u);
    return (a >> 16) | (b & 0xFFFF0000u);
}

__global__ __launch_bounds__(256, 4) void gram_tri(const float* __restrict__ x,
                                                   float* __restrict__ out) {
    __shared__ __align__(16) unsigned short sbuf[2][FF * LSTR];  // 2 × 17.4 KB
    const int t = threadIdx.x;
    const int wave = t >> 6;
    const int lane = t & 63;
    const int b0 = blockIdx.x * ROWS;

    const int qi = wave >> 1, qj = wave & 1;   // wave 2 = (1,0) lower quadrant: skipped
    const unsigned short* ldsA0 = &sbuf[0][(qi * 32 + (lane & 31)) * LSTR + ((lane >> 5) << 3)];
    const unsigned short* ldsB0 = &sbuf[0][(qj * 32 + (lane & 31)) * LSTR + ((lane >> 5) << 3)];
    const int bufoff = FF * LSTR;

    float4 sr[8];
    f32x16 acc;

    // ---- prologue: stage chunk 0 into buf 0 ----
    {
        const float4* __restrict__ src = (const float4*)(x + (size_t)b0 * (FF * DD));
#pragma unroll
        for (int it = 0; it < 8; ++it) {
            int lin = (it << 8) + t;                       // 0..2047
            sr[it] = src[((lin >> 5) << 6) + (lin & 31)];  // f*64 + kq (float4 units)
        }
#pragma unroll
        for (int it = 0; it < 8; ++it) {
            int lin = (it << 8) + t;
            int f = lin >> 5, kq = lin & 31;
            uint2 w;
            w.x = pack2(sr[it].x, sr[it].y);
            w.y = pack2(sr[it].z, sr[it].w);
            *(uint2*)&sbuf[0][f * LSTR + (kq << 2)] = w;
        }
    }
    __syncthreads();

#pragma unroll
    for (int s = 0; s < NCHUNK; ++s) {
        // 1) issue next chunk's global loads (stay in flight across MFMA)
        if (s + 1 < NCHUNK) {
            int nb = b0 + ((s + 1) >> 1);
            int kc = ((s + 1) & 1) * KC;
            const float4* __restrict__ src = (const float4*)(x + (size_t)nb * (FF * DD) + kc);
#pragma unroll
            for (int it = 0; it < 8; ++it) {
                int lin = (it << 8) + t;
                sr[it] = src[((lin >> 5) << 6) + (lin & 31)];
            }
        }
        // 2) MFMA on current buffer
        if ((s & 1) == 0) {
#pragma unroll
            for (int i = 0; i < 16; ++i) acc[i] = 0.0f;
        }
        if (wave != 2) {
            const unsigned short* pA = ldsA0 + (s & 1) * bufoff;
            const unsigned short* pB = ldsB0 + (s & 1) * bufoff;
#pragma unroll
            for (int ko = 0; ko < KC; ko += 16) {
                short8 a  = *(const short8*)(pA + ko);   // 16B-aligned ds_read_b128, conflict-free
                short8 bb = *(const short8*)(pB + ko);
                acc = __builtin_amdgcn_mfma_f32_32x32x16_bf16(a, bb, acc, 0, 0, 0);
            }
        }
        // 3) convert + write next chunk into the other buffer
        if (s + 1 < NCHUNK) {
            unsigned short* dst = &sbuf[0][((s + 1) & 1) * bufoff];
#pragma unroll
            for (int it = 0; it < 8; ++it) {
                int lin = (it << 8) + t;
                int f = lin >> 5, kq = lin & 31;
                uint2 w;
                w.x = pack2(sr[it].x, sr[it].y);
                w.y = pack2(sr[it].z, sr[it].w);
                *(uint2*)&dst[f * LSTR + (kq << 2)] = w;
            }
        }
        __syncthreads();
        // 4) epilogue after a row's second chunk (reads only registers)
        if ((s & 1) && wave != 2) {
            int b = b0 + (s >> 1);
            float* __restrict__ ob = out + (size_t)b * NPAIR;
#pragma unroll
            for (int reg = 0; reg < 16; ++reg) {
                // C/D layout (m74/m101): col=lane&31, row=(reg&3)+8*(reg>>2)+4*(lane>>5)
                int i = (qi << 5) + (reg & 3) + ((reg >> 2) << 3) + ((lane >> 5) << 2);
                int j = (qj << 5) + (lane & 31);
                if (i < j) ob[i * 63 - ((i * (i - 1)) >> 1) + (j - i - 1)] = acc[reg];
            }
        }
    }
}

extern "C" void kernel_launch(void* const* d_in, const int* in_sizes, int n_in,
                              void* d_out, int out_size, void* d_ws, size_t ws_size,
                              hipStream_t stream) {
    const float* x = (const float*)d_in[0];
    float* out = (float*)d_out;
    gram_tri<<<4096 / ROWS, 256, 0, stream>>>(x, out);
}